// Round 2
// baseline (2567.770 us; speedup 1.0000x reference)
//
#include <hip/hip_runtime.h>
#include <cstdint>
#include <cstddef>

// ---------------- problem constants ----------------
#define BATCH   128
#define SEQ     512
#define TOKENS  (BATCH * SEQ)   // 65536
#define EMB_D   300
#define KA0     320             // padded E
#define HID     256
#define G4H     1024            // 4*H
#define KA1     512             // 2*H
#define NTAGS   9
#define CHUNK   128             // seq chunk per round
#define CTOK    (BATCH * CHUNK) // 16384 rows per dir per round

typedef _Float16 f16;
typedef _Float16 f16x2 __attribute__((ext_vector_type(2)));
typedef _Float16 f16x8 __attribute__((ext_vector_type(8)));
typedef float    f32x4 __attribute__((ext_vector_type(4)));

// ---------------- workspace layout (bytes), total ~202 MB ----------------
static constexpr size_t XW_BYTES   = (size_t)2 * CTOK * G4H * 2;    // 67,108,864
static constexpr size_t H_BYTES    = (size_t)TOKENS * KA1 * 2;      // 67,108,864
static constexpr size_t POOL_BYTES = H_BYTES;                       // e16 (40MB) then h1 (64MB)
static constexpr size_t EM_BYTES   = (size_t)TOKENS * 16 * 4;       // 4,194,304
static constexpr size_t WHH_BYTES  = (size_t)4 * G4H * HID * 2;     // 2,097,152
static constexpr size_t WIH0_BYTES = (size_t)2 * G4H * KA0 * 2;     // 1,310,720
static constexpr size_t WIH1_BYTES = (size_t)2 * G4H * KA1 * 2;     // 2,097,152
static constexpr size_t FCW_BYTES  = (size_t)128 * KA1 * 2;         // 131,072
static constexpr size_t FCB_BYTES  = 512;
static constexpr size_t STH_BYTES  = (size_t)2 * BATCH * HID * 2;   // 131,072
static constexpr size_t STC_BYTES  = (size_t)2 * BATCH * HID * 4;   // 262,144
static constexpr size_t NLL_BYTES  = 512;

static constexpr size_t OFF_XW   = 0;
static constexpr size_t OFF_H0   = OFF_XW   + XW_BYTES;
static constexpr size_t OFF_POOL = OFF_H0   + H_BYTES;    // e16 and h1 alias here
static constexpr size_t OFF_EM   = OFF_POOL + POOL_BYTES;
static constexpr size_t OFF_WHH  = OFF_EM   + EM_BYTES;
static constexpr size_t OFF_WIH0 = OFF_WHH  + WHH_BYTES;
static constexpr size_t OFF_WIH1 = OFF_WIH0 + WIH0_BYTES;
static constexpr size_t OFF_FCW  = OFF_WIH1 + WIH1_BYTES;
static constexpr size_t OFF_FCB  = OFF_FCW  + FCW_BYTES;
static constexpr size_t OFF_STH  = OFF_FCB  + FCB_BYTES;
static constexpr size_t OFF_STC  = OFF_STH  + STH_BYTES;
static constexpr size_t OFF_NLL  = OFF_STC  + STC_BYTES;
static constexpr size_t WS_NEEDED = OFF_NLL + NLL_BYTES;  // ~202 MB

// ---------------- helpers ----------------
__device__ inline float fdot2(uint32_t a, uint32_t b, float c) {
#if __has_builtin(__builtin_amdgcn_fdot2)
  return __builtin_amdgcn_fdot2(__builtin_bit_cast(f16x2, a),
                                __builtin_bit_cast(f16x2, b), c, false);
#else
  f16x2 ha = __builtin_bit_cast(f16x2, a), hb = __builtin_bit_cast(f16x2, b);
  return c + (float)ha.x * (float)hb.x + (float)ha.y * (float)hb.y;
#endif
}

// LDS chunk swizzle to spread b128 frag reads across banks
__device__ inline int swz(int r, int q) { return q ^ ((r & 3) ^ ((r >> 2) & 3)); }

// ---------------- prep: fp32 -> fp16 weight packing ----------------
__global__ void prep_kernel(
    const float* whh_l0f, const float* whh_l0b, const float* whh_l1f, const float* whh_l1b,
    const float* wih_l0f, const float* wih_l0b,
    const float* wih_l1f, const float* wih_l1b,
    const float* fc_w, const float* fc_b,
    f16* whh16, f16* wih0_16, f16* wih1_16, f16* fcw16, float* fcb32)
{
  int id = blockIdx.x * 256 + threadIdx.x;
  if (id < 1048576) {               // whh: [4][1024][256]
    int which = id >> 18; int off = id & 262143;
    const float* s = which == 0 ? whh_l0f : which == 1 ? whh_l0b
                   : which == 2 ? whh_l1f : whh_l1b;
    whh16[id] = (f16)s[off];
    return;
  }
  id -= 1048576;
  if (id < 655360) {                // wih l0 padded: [2][1024][320]
    int dir = id / 327680; int rem = id - dir * 327680;
    int r = rem / KA0; int k = rem - r * KA0;
    const float* s = dir ? wih_l0b : wih_l0f;
    wih0_16[id] = (f16)(k < EMB_D ? s[r * EMB_D + k] : 0.f);
    return;
  }
  id -= 655360;
  if (id < 1048576) {               // wih l1: [2][1024][512]
    const float* s = (id < 524288) ? wih_l1f : wih_l1b;
    wih1_16[id] = (f16)s[id & 524287];
    return;
  }
  id -= 1048576;
  if (id < 65536) {                 // fcw: [128][512], rows >= 9 zero
    int r = id >> 9;
    fcw16[id] = (f16)(r < NTAGS ? fc_w[id] : 0.f);
    return;
  }
  id -= 65536;
  if (id < 128) fcb32[id] = id < NTAGS ? fc_b[id] : 0.f;
}

// ---------------- embedding gather -> f16 padded ----------------
__global__ void embed_kernel(const int* __restrict__ x, const float* __restrict__ emb,
                             f16* __restrict__ e16)
{
  int id = blockIdx.x * 256 + threadIdx.x;   // over TOKENS*KA0
  if (id >= TOKENS * KA0) return;
  int row = id / KA0, k = id - row * KA0;
  float v = 0.f;
  if (k < EMB_D) v = emb[(size_t)x[row] * EMB_D + k];
  e16[id] = (f16)v;
}

// ---------------- MFMA f16 GEMM: C[M][N] = A[rowmap(M)][K] * B[N][K]^T + bias ----
// 128x128 tile, BK=32, 256 threads (4 waves, 2x2 of 64x64).
// A row for C row m: (m>>7)*aGrpStride + cb + (m&127). gridDim.z selects
// (B,bias,cb,out-offset) pair for the two LSTM directions.
__global__ __launch_bounds__(256, 3) void gemm_kernel(
    const f16* __restrict__ A, int lda, int aGrpStride,
    const f16* __restrict__ B0, const f16* __restrict__ B1, int ldb,
    const float* __restrict__ bias0, const float* __restrict__ bias1,
    f16* outH, float* outF, int ldc, size_t outZStride,
    int kChunks, int nLimit, int cbF, int cbB)
{
  __shared__ __align__(16) f16 As[128 * 32];
  __shared__ __align__(16) f16 Bs[128 * 32];
  const int z = blockIdx.z;
  const f16* B = z ? B1 : B0;
  const float* bias = z ? bias1 : bias0;
  const int cb = z ? cbB : cbF;
  const int m0 = blockIdx.x * 128, n0 = blockIdx.y * 128;
  const int aBase = (m0 >> 7) * aGrpStride + cb;
  const int tid = threadIdx.x;
  const int w = tid >> 6, lane = tid & 63;
  const int mw = (w & 1) * 64, nw = (w >> 1) * 64;
  const int fr = lane & 15, fq = lane >> 4;

  f32x4 acc[4][4];
#pragma unroll
  for (int i = 0; i < 4; ++i)
#pragma unroll
    for (int j = 0; j < 4; ++j) acc[i][j] = (f32x4)(0.f);

  const int c0 = tid, c1 = tid + 256;
  const int r0 = c0 >> 2, q0 = c0 & 3, r1c = c1 >> 2, q1 = c1 & 3;

  for (int kc = 0; kc < kChunks; ++kc) {
    const int k0 = kc * 32;
    uint4 a0v = *(const uint4*)(A + (size_t)(aBase + r0)  * lda + k0 + q0 * 8);
    uint4 a1v = *(const uint4*)(A + (size_t)(aBase + r1c) * lda + k0 + q1 * 8);
    uint4 b0v = *(const uint4*)(B + (size_t)(n0 + r0)  * ldb + k0 + q0 * 8);
    uint4 b1v = *(const uint4*)(B + (size_t)(n0 + r1c) * ldb + k0 + q1 * 8);
    __syncthreads();
    *(uint4*)(As + r0  * 32 + swz(r0,  q0) * 8) = a0v;
    *(uint4*)(As + r1c * 32 + swz(r1c, q1) * 8) = a1v;
    *(uint4*)(Bs + r0  * 32 + swz(r0,  q0) * 8) = b0v;
    *(uint4*)(Bs + r1c * 32 + swz(r1c, q1) * 8) = b1v;
    __syncthreads();
    f16x8 af[4], bf[4];
#pragma unroll
    for (int i = 0; i < 4; ++i) {
      int rr = mw + i * 16 + fr;
      af[i] = *(const f16x8*)(As + rr * 32 + swz(rr, fq) * 8);
    }
#pragma unroll
    for (int j = 0; j < 4; ++j) {
      int rr = nw + j * 16 + fr;
      bf[j] = *(const f16x8*)(Bs + rr * 32 + swz(rr, fq) * 8);
    }
#pragma unroll
    for (int i = 0; i < 4; ++i)
#pragma unroll
      for (int j = 0; j < 4; ++j)
        acc[i][j] = __builtin_amdgcn_mfma_f32_16x16x32_f16(af[i], bf[j], acc[i][j], 0, 0, 0);
  }
  // epilogue: C row = (lane>>4)*4 + r, col = lane&15
  f16* oH = outH ? outH + (size_t)z * outZStride : nullptr;
  float* oF = outF;
#pragma unroll
  for (int j = 0; j < 4; ++j) {
    int n = n0 + nw + j * 16 + fr;
    if (n >= nLimit) continue;
    float bs = bias ? bias[n] : 0.f;
#pragma unroll
    for (int i = 0; i < 4; ++i) {
#pragma unroll
      for (int r = 0; r < 4; ++r) {
        int m = m0 + mw + i * 16 + fq * 4 + r;
        float v = acc[i][j][r] + bs;
        if (oH) oH[(size_t)m * ldc + n] = (f16)v;
        else    oF[(size_t)m * ldc + n] = v;
      }
    }
  }
}

// ---------------- persistent LSTM recurrence, 128-step chunk ----------------
// grid 256 = (dir, batch); 512 threads; thread owns gate rows 2t,2t+1.
// Whh cols [0,192) in VGPRs, cols [192,256) in LDS (128 KB).
// Round r: fwd processes chunk r (ascending t), bwd chunk 3-r (descending t).
__global__ __launch_bounds__(512, 2) void rec_kernel(
    const uint32_t* __restrict__ xw,       // [2][128][CHUNK][512] uint32
    const uint32_t* __restrict__ whh_f, const uint32_t* __restrict__ whh_b,
    f16* __restrict__ hout,
    f16* __restrict__ stateH, float* __restrict__ stateC, int r)
{
  __shared__ __align__(16) uint4 wlds[16 * 512];   // 128 KB
  __shared__ float gates[1024];                    // 4 KB
  __shared__ __align__(16) f16 hbuf[2][256];       // 1 KB
  const int tau = threadIdx.x;
  const int bid = blockIdx.x;
  const int dir = bid >> 7;
  const int b   = bid & 127;
  const int chunk = dir ? (3 - r) : r;
  const int tBase = chunk * CHUNK;
  const uint32_t* whh = dir ? whh_b : whh_f;
  const uint32_t* xwp = xw + (size_t)(dir * 128 + b) * CHUNK * 512;

  const int row0 = 2 * tau, row1 = 2 * tau + 1;
  uint4 wa4[24], wb4[24];
  {
    const uint4* p0 = (const uint4*)(whh + row0 * 128);
    const uint4* p1 = (const uint4*)(whh + row1 * 128);
#pragma unroll
    for (int i = 0; i < 24; ++i) { wa4[i] = p0[i]; wb4[i] = p1[i]; }
#pragma unroll
    for (int c = 0; c < 16; ++c) {
      uint4 v;
      v.x = whh[row0 * 128 + 96 + 2 * c]; v.y = whh[row0 * 128 + 97 + 2 * c];
      v.z = whh[row1 * 128 + 96 + 2 * c]; v.w = whh[row1 * 128 + 97 + 2 * c];
      wlds[c * 512 + tau] = v;
    }
  }
  float cst = 0.f;
  if (tau < 256) {
    f16 hi = (f16)0.f;
    if (r) { hi = stateH[(dir * 128 + b) * 256 + tau]; cst = stateC[(dir * 128 + b) * 256 + tau]; }
    hbuf[0][tau] = hi;
  }
  __syncthreads();

  int lr0 = dir ? (CHUNK - 1) : 0;
  uint32_t xw_cur = xwp[lr0 * 512 + tau];

  for (int s = 0; s < CHUNK; ++s) {
    const int lrow = dir ? (CHUNK - 1 - s) : s;
    const size_t token = (size_t)b * 512 + tBase + lrow;
    const int cur = s & 1, nxt = cur ^ 1;
    // prefetch next step's xW (independent of recurrence)
    uint32_t xw_nextv = 0;
    if (s < CHUNK - 1) {
      int lrn = dir ? (CHUNK - 2 - s) : (s + 1);
      xw_nextv = xwp[lrn * 512 + tau];
    }
    f16x2 xh = __builtin_bit_cast(f16x2, xw_cur);
    float a0 = (float)xh.x, a1 = (float)xh.y;
    const uint4* hb4 = (const uint4*)hbuf[cur];
#pragma unroll
    for (int i = 0; i < 24; ++i) {
      uint4 hv = hb4[i];  // broadcast read: all lanes same address
      a0 = fdot2(wa4[i].x, hv.x, a0);
      a0 = fdot2(wa4[i].y, hv.y, a0);
      a0 = fdot2(wa4[i].z, hv.z, a0);
      a0 = fdot2(wa4[i].w, hv.w, a0);
      a1 = fdot2(wb4[i].x, hv.x, a1);
      a1 = fdot2(wb4[i].y, hv.y, a1);
      a1 = fdot2(wb4[i].z, hv.z, a1);
      a1 = fdot2(wb4[i].w, hv.w, a1);
    }
#pragma unroll
    for (int c2 = 0; c2 < 8; ++c2) {
      uint4 hv = hb4[24 + c2];
      uint4 w0 = wlds[(2 * c2) * 512 + tau];
      uint4 w1 = wlds[(2 * c2 + 1) * 512 + tau];
      a0 = fdot2(w0.x, hv.x, a0); a0 = fdot2(w0.y, hv.y, a0);
      a1 = fdot2(w0.z, hv.x, a1); a1 = fdot2(w0.w, hv.y, a1);
      a0 = fdot2(w1.x, hv.z, a0); a0 = fdot2(w1.y, hv.w, a0);
      a1 = fdot2(w1.z, hv.z, a1); a1 = fdot2(w1.w, hv.w, a1);
    }
    gates[row0] = a0; gates[row1] = a1;
    __syncthreads();
    if (tau < 256) {
      float gi = gates[tau], gf = gates[256 + tau], gg = gates[512 + tau], go = gates[768 + tau];
      float si = 1.f / (1.f + __expf(-gi));
      float sf = 1.f / (1.f + __expf(-gf));
      float so = 1.f / (1.f + __expf(-go));
      float e2 = __expf(2.f * gg); float tg = 1.f - 2.f / (e2 + 1.f);
      cst = sf * cst + si * tg;
      e2 = __expf(2.f * cst); float tc = 1.f - 2.f / (e2 + 1.f);
      float h = so * tc;
      f16 hh = (f16)h;
      hbuf[nxt][tau] = hh;
      hout[token * 512 + dir * 256 + tau] = hh;
    }
    __syncthreads();
    xw_cur = xw_nextv;
  }
  // CHUNK is even -> final h is in hbuf[0]
  if (tau < 256) {
    stateH[(dir * 128 + b) * 256 + tau] = hbuf[0][tau];
    stateC[(dir * 128 + b) * 256 + tau] = cst;
  }
}

// ---------------- CRF: one wave per batch element ----------------
__global__ void crf_kernel(const float* __restrict__ em, const int* __restrict__ tags,
                           const float* __restrict__ start, const float* __restrict__ endv,
                           const float* __restrict__ trans, float* __restrict__ nll)
{
  const int b = blockIdx.x;
  const int lane = threadIdx.x;  // 64
  const float* emb_ = em + (size_t)b * SEQ * 16;
  const int* tg = tags + b * SEQ;

  // numerator, parallel over t
  float numacc = 0.f;
  for (int t = lane; t < SEQ; t += 64) {
    int ct = tg[t];
    numacc += emb_[t * 16 + ct];
    if (t > 0) numacc += trans[tg[t - 1] * NTAGS + ct];
  }
#pragma unroll
  for (int s = 32; s; s >>= 1) numacc += __shfl_xor(numacc, s);

  // forward algorithm: lanes 0..8 hold alpha_j
  int jj = lane < NTAGS ? lane : 0;
  float tr[NTAGS];
#pragma unroll
  for (int i = 0; i < NTAGS; ++i) tr[i] = trans[i * NTAGS + jj];
  float alpha = (lane < NTAGS) ? (start[lane] + emb_[lane]) : -1e30f;
  for (int t = 1; t < SEQ; ++t) {
    float va[NTAGS];
#pragma unroll
    for (int i = 0; i < NTAGS; ++i) va[i] = __shfl(alpha, i) + tr[i];
    float mx = va[0];
#pragma unroll
    for (int i = 1; i < NTAGS; ++i) mx = fmaxf(mx, va[i]);
    float s = 0.f;
#pragma unroll
    for (int i = 0; i < NTAGS; ++i) s += __expf(va[i] - mx);
    float na = mx + __logf(s) + emb_[t * 16 + jj];
    alpha = (lane < NTAGS) ? na : -1e30f;
  }
  float v = (lane < NTAGS) ? alpha + endv[lane] : -1e30f;
  float mx = v;
#pragma unroll
  for (int s2 = 32; s2; s2 >>= 1) mx = fmaxf(mx, __shfl_xor(mx, s2));
  float se = __expf(v - mx);
#pragma unroll
  for (int s2 = 32; s2; s2 >>= 1) se += __shfl_xor(se, s2);
  float denom = mx + __logf(se);
  if (lane == 0) {
    float num = numacc + start[tg[0]] + endv[tg[SEQ - 1]];
    nll[b] = denom - num;
  }
}

__global__ void reduce_kernel(const float* __restrict__ nll, float* __restrict__ out) {
  int lane = threadIdx.x;  // 64
  float v = nll[lane] + nll[lane + 64];
#pragma unroll
  for (int s = 32; s; s >>= 1) v += __shfl_xor(v, s);
  if (lane == 0) out[0] = v * (1.f / 128.f);
}

// ---------------- launch ----------------
extern "C" void kernel_launch(void* const* d_in, const int* in_sizes, int n_in,
                              void* d_out, int out_size, void* d_ws, size_t ws_size,
                              hipStream_t stream)
{
  const int*   x        = (const int*)d_in[0];
  const int*   tags     = (const int*)d_in[1];
  const float* emb      = (const float*)d_in[2];
  const float* wih_l0f  = (const float*)d_in[3];
  const float* whh_l0f  = (const float*)d_in[4];
  const float* b_l0f    = (const float*)d_in[5];
  const float* wih_l0b  = (const float*)d_in[6];
  const float* whh_l0b  = (const float*)d_in[7];
  const float* b_l0b    = (const float*)d_in[8];
  const float* wih_l1f  = (const float*)d_in[9];
  const float* whh_l1f  = (const float*)d_in[10];
  const float* b_l1f    = (const float*)d_in[11];
  const float* wih_l1b  = (const float*)d_in[12];
  const float* whh_l1b  = (const float*)d_in[13];
  const float* b_l1b    = (const float*)d_in[14];
  const float* fc_w     = (const float*)d_in[15];
  const float* fc_b     = (const float*)d_in[16];
  const float* crf_start= (const float*)d_in[17];
  const float* crf_end  = (const float*)d_in[18];
  const float* crf_trans= (const float*)d_in[19];

  char* ws = (char*)d_ws;
  f16*   xw16   = (f16*)(ws + OFF_XW);
  f16*   h0     = (f16*)(ws + OFF_H0);
  f16*   e16    = (f16*)(ws + OFF_POOL);   // 40 MB, dead after layer-0 GEMMs
  f16*   h1     = (f16*)(ws + OFF_POOL);   // 64 MB, written during layer-1 rec
  float* em32   = (float*)(ws + OFF_EM);
  f16*   whh16  = (f16*)(ws + OFF_WHH);
  f16*   wih016 = (f16*)(ws + OFF_WIH0);
  f16*   wih116 = (f16*)(ws + OFF_WIH1);
  f16*   fcw16  = (f16*)(ws + OFF_FCW);
  float* fcb32  = (float*)(ws + OFF_FCB);
  f16*   stH    = (f16*)(ws + OFF_STH);
  float* stC    = (float*)(ws + OFF_STC);
  float* nllbuf = (float*)(ws + OFF_NLL);
  const uint32_t* xw32  = (const uint32_t*)xw16;
  const uint32_t* whh32 = (const uint32_t*)whh16;

  // 1) weight packing + embedding gather
  prep_kernel<<<11009, 256, 0, stream>>>(whh_l0f, whh_l0b, whh_l1f, whh_l1b,
                                         wih_l0f, wih_l0b, wih_l1f, wih_l1b,
                                         fc_w, fc_b, whh16, wih016, wih116, fcw16, fcb32);
  embed_kernel<<<(TOKENS * KA0) / 256, 256, 0, stream>>>(x, emb, e16);

  const size_t zstr = (size_t)CTOK * G4H;
  dim3 gch(CTOK / 128, G4H / 128, 2);

  // 2) layer 0: 4 rounds of (chunk GEMM fwd+bwd, 128-step rec)
  for (int r = 0; r < 4; ++r) {
    gemm_kernel<<<gch, 256, 0, stream>>>(e16, KA0, SEQ,
                                         wih016, wih016 + (size_t)G4H * KA0, KA0,
                                         b_l0f, b_l0b, xw16, nullptr, G4H, zstr,
                                         KA0 / 32, G4H, r * CHUNK, (3 - r) * CHUNK);
    rec_kernel<<<256, 512, 0, stream>>>(xw32, whh32, whh32 + (size_t)G4H * 128,
                                        h0, stH, stC, r);
  }

  // 3) layer 1: same, input = h0
  for (int r = 0; r < 4; ++r) {
    gemm_kernel<<<gch, 256, 0, stream>>>(h0, KA1, SEQ,
                                         wih116, wih116 + (size_t)G4H * KA1, KA1,
                                         b_l1f, b_l1b, xw16, nullptr, G4H, zstr,
                                         KA1 / 32, G4H, r * CHUNK, (3 - r) * CHUNK);
    rec_kernel<<<256, 512, 0, stream>>>(xw32, whh32 + (size_t)2 * G4H * 128,
                                        whh32 + (size_t)3 * G4H * 128,
                                        h1, stH, stC, r);
  }

  // 4) FC emissions (N padded to 128, store first 16 cols as f32)
  dim3 gfc(TOKENS / 128, 1, 1);
  gemm_kernel<<<gfc, 256, 0, stream>>>(h1, KA1, 128,
                                       fcw16, nullptr, KA1, fcb32, nullptr,
                                       nullptr, em32, 16, 0, KA1 / 32, 16, 0, 0);

  // 5) CRF nll per batch + mean
  crf_kernel<<<BATCH, 64, 0, stream>>>(em32, tags, crf_start, crf_end, crf_trans, nllbuf);
  reduce_kernel<<<1, 64, 0, stream>>>(nllbuf, (float*)d_out);
}